// Round 1
// 166.682 us; speedup vs baseline: 1.0108x; 1.0108x over previous
//
#include <hip/hip_runtime.h>
#include <hip/hip_bf16.h>

// GAT layer: N=4096, F_IN=128, F_OUT=64, HEADS=4.
// R12: fuse the column-split away. gat_main blocks now own FULL rows
// (32 rows x 4096 cols, one head): 8 waves = 2 row-groups x 4-way K-split,
// 32 double-buffered 128-col chunks (async reg-stage -> ds_write, 1 barrier
// per chunk), in-LDS K-partial reduction, normalization fused into the
// epilogue. This deletes the 33.5 MB Hpart + 0.5 MB lpartP round-trip and
// the latency-bound 37.5 MB gat_fin read (fin is now a 5 MB 4-head sum).
// Grid 512 x 512thr = 2 blocks/CU (LDS 59 KB/block), launch_bounds(512,4)
// caps VGPR at 128 for 16 waves/CU.
// Kernels: pack_bits -> gat_prep -> gat_main (fused) -> gat_fin (tiny).

#define NN 4096
#define FIN 128
#define FOUT 64
#define NH 4

typedef __attribute__((ext_vector_type(8))) short bf16x8;
typedef __attribute__((ext_vector_type(4))) float f32x4;
typedef __attribute__((ext_vector_type(4))) unsigned int u32x4;

__device__ __forceinline__ unsigned short f32_bf16(float f) {
    unsigned u = __builtin_bit_cast(unsigned, f);
    u += 0x7fffu + ((u >> 16) & 1u);          // round-to-nearest-even
    return (unsigned short)(u >> 16);
}

// ---------------- Kernel 0: pack A (int32 0/1) into bitmask ----------------
__global__ __launch_bounds__(256) void pack_bits(
    const int* __restrict__ A, unsigned long long* __restrict__ Abits)
{
    const int row  = blockIdx.x;
    const int lane = threadIdx.x & 63;
    const int wv   = threadIdx.x >> 6;
    const int* arow = A + (size_t)row * NN;
    #pragma unroll 4
    for (int c = 0; c < 16; ++c) {
        const int col = c * 256 + wv * 64 + lane;
        unsigned long long m = __ballot(__builtin_nontemporal_load(&arow[col]) > 0);
        if (lane == 0) Abits[(size_t)row * 64 + c * 4 + wv] = m;
    }
}

// ---------------- Kernel 1: prep ----------------
__global__ __launch_bounds__(256) void gat_prep(
    const float* __restrict__ X, const float* __restrict__ W,
    const float* __restrict__ b, const float* __restrict__ att,
    unsigned short* __restrict__ HbfT, float* __restrict__ Hrow,
    float* __restrict__ s_out, float* __restrict__ d_out,
    float* __restrict__ es_g, float* __restrict__ es2_g,
    float* __restrict__ ed_g, float* __restrict__ ed2_g)
{
    const int rb = blockIdx.x;           // 0..127
    const int h  = blockIdx.y;           // 0..3
    const int n0 = rb * 32;
    const int t  = threadIdx.x;          // 0..255

    __shared__ float Xl[32][132];
    __shared__ float Wt[128][68];

    for (int g = t; g < 32 * 32; g += 256) {
        int row = g >> 5, c4 = g & 31;
        float4 v = *(const float4*)&X[(size_t)(n0 + row) * FIN + c4 * 4];
        *(float4*)&Xl[row][c4 * 4] = v;
    }
    for (int g = t; g < 64 * 32; g += 256) {
        int o = g >> 5, c4 = g & 31;
        float4 v = *(const float4*)&W[((size_t)h * FOUT + o) * FIN + c4 * 4];
        Wt[c4 * 4 + 0][o] = v.x; Wt[c4 * 4 + 1][o] = v.y;
        Wt[c4 * 4 + 2][o] = v.z; Wt[c4 * 4 + 3][o] = v.w;
    }
    __syncthreads();

    const int rg = t >> 4;               // rows rg*2 .. rg*2+1
    const int og = t & 15;               // cols og*4 .. og*4+3
    float acc[2][4] = {};

    #pragma unroll 4
    for (int f4 = 0; f4 < 32; ++f4) {
        float xv[2][4], wv[4][4];
        #pragma unroll
        for (int i = 0; i < 2; ++i) {
            float4 tmp = *(const float4*)&Xl[rg * 2 + i][f4 * 4];
            xv[i][0] = tmp.x; xv[i][1] = tmp.y; xv[i][2] = tmp.z; xv[i][3] = tmp.w;
        }
        #pragma unroll
        for (int k = 0; k < 4; ++k) {
            float4 tmp = *(const float4*)&Wt[f4 * 4 + k][og * 4];
            wv[k][0] = tmp.x; wv[k][1] = tmp.y; wv[k][2] = tmp.z; wv[k][3] = tmp.w;
        }
        #pragma unroll
        for (int i = 0; i < 2; ++i)
            #pragma unroll
            for (int k = 0; k < 4; ++k)
                #pragma unroll
                for (int jj = 0; jj < 4; ++jj)
                    acc[i][jj] = fmaf(xv[i][k], wv[k][jj], acc[i][jj]);
    }

    float bb[4], as_[4], ad_[4];
    #pragma unroll
    for (int jj = 0; jj < 4; ++jj) {
        bb[jj]  = b[h * FOUT + og * 4 + jj];
        as_[jj] = att[h * 2 * FOUT + og * 4 + jj];
        ad_[jj] = att[h * 2 * FOUT + FOUT + og * 4 + jj];
    }
    #pragma unroll
    for (int i = 0; i < 2; ++i)
        #pragma unroll
        for (int jj = 0; jj < 4; ++jj)
            acc[i][jj] += bb[jj];

    float sp[2] = {0.f, 0.f}, dp[2] = {0.f, 0.f};
    #pragma unroll
    for (int i = 0; i < 2; ++i)
        #pragma unroll
        for (int jj = 0; jj < 4; ++jj) {
            sp[i] = fmaf(acc[i][jj], as_[jj], sp[i]);
            dp[i] = fmaf(acc[i][jj], ad_[jj], dp[i]);
        }
    #pragma unroll
    for (int off = 1; off < 16; off <<= 1) {
        #pragma unroll
        for (int i = 0; i < 2; ++i) {
            sp[i] += __shfl_xor(sp[i], off);
            dp[i] += __shfl_xor(dp[i], off);
        }
    }
    if (og == 0) {
        #pragma unroll
        for (int i = 0; i < 2; ++i) {
            int nn = n0 + rg * 2 + i;
            s_out[h * NN + nn]  = sp[i];
            d_out[h * NN + nn]  = dp[i];
            es_g [h * NN + nn]  = __expf(sp[i]);
            es2_g[h * NN + nn]  = __expf(0.01f * sp[i]);
            ed_g [h * NN + nn]  = __expf(dp[i]);
            ed2_g[h * NN + nn]  = __expf(0.01f * dp[i]);
        }
    }

    #pragma unroll
    for (int i = 0; i < 2; ++i) {
        float4 v = make_float4(acc[i][0], acc[i][1], acc[i][2], acc[i][3]);
        *(float4*)&Hrow[((size_t)h * NN + n0 + rg * 2 + i) * FOUT + og * 4] = v;
    }
    #pragma unroll
    for (int jj = 0; jj < 4; ++jj) {
        int o = og * 4 + jj;
        ushort2 p;
        p.x = f32_bf16(acc[0][jj]);
        p.y = f32_bf16(acc[1][jj]);
        *(ushort2*)&HbfT[((size_t)h * FOUT + o) * NN + n0 + rg * 2] = p;
    }
}

// ---------------- Kernel 2: fused masked softmax-aggregate ------------------
// Grid 512 x 512thr. id -> h = id&3 (XCD-affine: each XCD serves one head),
// tile = id>>2 (32 rows). 8 waves: rg = w&1 (rows rg*16..), kg = w>>1
// (4-way K-split: wave kg computes step kg of every 128-col chunk).
// 32 chunks x 128 cols, double-buffered LDS, one barrier per chunk.
// Epilogue: K-partial reduction in LDS, then fused normalize + diag + store.
__global__ __launch_bounds__(512, 4) void gat_main(
    const unsigned* __restrict__ Abits, const unsigned short* __restrict__ HbfT,
    const float* __restrict__ s_g, const float* __restrict__ d_g,
    const float* __restrict__ es_g, const float* __restrict__ es2_g,
    const float* __restrict__ ed_g, const float* __restrict__ ed2_g,
    const float* __restrict__ Hrow, float* __restrict__ outH)
{
    const int id   = blockIdx.x;         // 0..511
    const int h    = id & 3;
    const int tile = id >> 2;            // 0..127
    const int n0   = tile * 32;
    const int tid  = threadIdx.x;        // 0..511
    const int w    = tid >> 6;           // wave 0..7
    const int lane = tid & 63;
    const int r    = lane & 15;          // A row within 16-row group / C col
    const int q    = lane >> 4;          // quad
    const int qs   = q * 8;
    const int rg   = w & 1;              // row group
    const int kg   = w >> 1;             // K-split group (step index)

    __shared__ __align__(16) unsigned short Hlds[2][64][128];  // 32 KB dbuf
    __shared__ unsigned bits_lds[2][32 * 5];                   // 1.25 KB
    __shared__ float red[6][16][68];                           // 25.5 KB (pad 68)
    __shared__ float redl[6][16];

    const int nrow = n0 + rg * 16 + r;   // row this lane's A-fragment covers
    const float es  = es_g [h * NN + nrow];
    const float es2 = es2_g[h * NN + nrow];

    // constant per-lane addresses
    const int mb       = (kg * 4 + q) ^ r;            // swizzled 16B block idx
    const int bits_idx = (rg * 16 + r) * 5 + kg;

    // staging roles: 512 threads cover 64 o-rows x 16 c16-blocks (2 each)
    const int so = tid >> 4;             // 0..31
    const int sc = tid & 15;             // c16
    const unsigned short* srcA = HbfT + ((size_t)(h * FOUT) + so)      * NN + sc * 8;
    const unsigned short* srcB = HbfT + ((size_t)(h * FOUT) + so + 32) * NN + sc * 8;
    const int offA = so * 128        + (sc ^ (so & 15)) * 8;
    const int offB = (so + 32) * 128 + (sc ^ (so & 15)) * 8;   // (so+32)&15==so&15
    const int brow = tid >> 2, bwd = tid & 3;                  // bits: 32 rows x 4 words
    const unsigned* srcBits = Abits + (size_t)(n0 + brow) * 128 + bwd;

    const float* edh  = ed_g  + h * NN + kg * 32 + qs;
    const float* ed2h = ed2_g + h * NN + kg * 32 + qs;

    bf16x8 ones;
    #pragma unroll
    for (int i = 0; i < 8; ++i) ones[i] = (short)0x3F80;   // bf16 1.0

    f32x4 acc0 = {0,0,0,0}, acc1 = {0,0,0,0}, acc2 = {0,0,0,0},
          acc3 = {0,0,0,0}, accl = {0,0,0,0};

    bf16x8 stA, stB;
    unsigned stBits = 0;

    // ---- prologue: stage chunk 0 into buffer 0 ----
    stA = *(const bf16x8*)&srcA[0];
    stB = *(const bf16x8*)&srcB[0];
    {
        unsigned short* hw = &Hlds[0][0][0];
        *(bf16x8*)(hw + offA) = stA;
        *(bf16x8*)(hw + offB) = stB;
        if (tid < 128) bits_lds[0][brow * 5 + bwd] = srcBits[0];
    }
    __syncthreads();

    for (int ch = 0; ch < 32; ++ch) {
        const int buf = ch & 1;
        const unsigned short* hb = buf ? &Hlds[1][0][0] : &Hlds[0][0][0];
        const unsigned*       bl = buf ? bits_lds[1]    : bits_lds[0];

        // issue next chunk's global loads early (latency hides under compute)
        if (ch < 31) {
            stA = *(const bf16x8*)&srcA[(ch + 1) * 128];
            stB = *(const bf16x8*)&srcB[(ch + 1) * 128];
            if (tid < 128) stBits = srcBits[(ch + 1) * 4];
        }

        // ---- edge weights for (16 rows x 32 cols) of this wave's step ----
        const unsigned bits8 = bl[bits_idx] >> qs;
        const int cb = ch * 128;
        const float4 e0 = *(const float4*)&edh [cb];
        const float4 e1 = *(const float4*)&edh [cb + 4];
        const float4 g0 = *(const float4*)&ed2h[cb];
        const float4 g1 = *(const float4*)&ed2h[cb + 4];
        const float edv [8] = {e0.x, e0.y, e0.z, e0.w, e1.x, e1.y, e1.z, e1.w};
        const float ed2v[8] = {g0.x, g0.y, g0.z, g0.w, g1.x, g1.y, g1.z, g1.w};

        u32x4 afu;
        #pragma unroll
        for (int p = 0; p < 4; ++p) {
            const int j0 = 2 * p, j1 = 2 * p + 1;
            float wa = (bits8 & (1u << j0))
                     ? fmaxf(es * edv[j0], es2 * ed2v[j0]) : 0.0f;
            float wb = (bits8 & (1u << j1))
                     ? fmaxf(es * edv[j1], es2 * ed2v[j1]) : 0.0f;
            __hip_bfloat162 pk = __float22bfloat162_rn(make_float2(wa, wb));
            unsigned u;
            __builtin_memcpy(&u, &pk, sizeof(u));   // v_cvt_pk path
            afu[p] = u;
        }
        const bf16x8 af = __builtin_bit_cast(bf16x8, afu);

        // B fragments from swizzled LDS
        const bf16x8 b0 = *(const bf16x8*)&hb[(r     ) * 128 + mb * 8];
        const bf16x8 b1 = *(const bf16x8*)&hb[(r + 16) * 128 + mb * 8];
        const bf16x8 b2 = *(const bf16x8*)&hb[(r + 32) * 128 + mb * 8];
        const bf16x8 b3 = *(const bf16x8*)&hb[(r + 48) * 128 + mb * 8];

        acc0 = __builtin_amdgcn_mfma_f32_16x16x32_bf16(af, b0,   acc0, 0, 0, 0);
        acc1 = __builtin_amdgcn_mfma_f32_16x16x32_bf16(af, b1,   acc1, 0, 0, 0);
        acc2 = __builtin_amdgcn_mfma_f32_16x16x32_bf16(af, b2,   acc2, 0, 0, 0);
        acc3 = __builtin_amdgcn_mfma_f32_16x16x32_bf16(af, b3,   acc3, 0, 0, 0);
        accl = __builtin_amdgcn_mfma_f32_16x16x32_bf16(af, ones, accl, 0, 0, 0);

        // write staged regs to the other buffer (consumers synced last barrier)
        if (ch < 31) {
            unsigned short* hw = buf ? &Hlds[0][0][0] : &Hlds[1][0][0];
            *(bf16x8*)(hw + offA) = stA;
            *(bf16x8*)(hw + offB) = stB;
            if (tid < 128) (buf ? bits_lds[0] : bits_lds[1])[brow * 5 + bwd] = stBits;
        }
        __syncthreads();
    }

    // ---- K-partial reduction: kg 1..3 dump to LDS, kg 0 accumulates ----
    if (kg > 0) {
        const int widx = (kg - 1) * 2 + rg;
        #pragma unroll
        for (int reg = 0; reg < 4; ++reg) {
            const int rr = q * 4 + reg;
            red[widx][rr][ 0 + r] = acc0[reg];
            red[widx][rr][16 + r] = acc1[reg];
            red[widx][rr][32 + r] = acc2[reg];
            red[widx][rr][48 + r] = acc3[reg];
        }
        if (r == 0) {
            #pragma unroll
            for (int reg = 0; reg < 4; ++reg)
                redl[widx][q * 4 + reg] = accl[reg];
        }
    }
    __syncthreads();
    if (kg == 0) {
        #pragma unroll
        for (int kk = 0; kk < 3; ++kk) {
            const int widx = kk * 2 + rg;
            #pragma unroll
            for (int reg = 0; reg < 4; ++reg) {
                const int rr = q * 4 + reg;
                acc0[reg] += red[widx][rr][ 0 + r];
                acc1[reg] += red[widx][rr][16 + r];
                acc2[reg] += red[widx][rr][32 + r];
                acc3[reg] += red[widx][rr][48 + r];
                accl[reg] += redl[widx][rr];
            }
        }
        // ---- fused normalize + diagonal + store per-head output ----
        #pragma unroll
        for (int reg = 0; reg < 4; ++reg) {
            const int rr  = q * 4 + reg;
            const int nn2 = n0 + rg * 16 + rr;
            const float tt = s_g[h * NN + nn2] + d_g[h * NN + nn2];
            const float wd = __expf(fmaxf(tt, 0.01f * tt));
            const float inv = 0.25f / (accl[reg] + wd);
            const float* hr = &Hrow[((size_t)h * NN + nn2) * FOUT];
            float*       ob = &outH[((size_t)h * NN + nn2) * FOUT];
            ob[ 0 + r] = (acc0[reg] + wd * hr[ 0 + r]) * inv;
            ob[16 + r] = (acc1[reg] + wd * hr[16 + r]) * inv;
            ob[32 + r] = (acc2[reg] + wd * hr[32 + r]) * inv;
            ob[48 + r] = (acc3[reg] + wd * hr[48 + r]) * inv;
        }
    }
}

// ---------------- Kernel 3: tiny finalize — sum 4 heads ----------------
__global__ __launch_bounds__(256) void gat_fin(
    const float* __restrict__ outH, float* __restrict__ out)
{
    const int i = blockIdx.x * 256 + threadIdx.x;    // 0..65535 float4s
    const f32x4* p = (const f32x4*)outH;
    f32x4 v0 = __builtin_nontemporal_load(p + i);
    f32x4 v1 = __builtin_nontemporal_load(p + i +  65536);
    f32x4 v2 = __builtin_nontemporal_load(p + i + 131072);
    f32x4 v3 = __builtin_nontemporal_load(p + i + 196608);
    f32x4 s = (v0 + v1) + (v2 + v3);
    *((f32x4*)out + i) = s;
}

extern "C" void kernel_launch(void* const* d_in, const int* in_sizes, int n_in,
                              void* d_out, int out_size, void* d_ws, size_t ws_size,
                              hipStream_t stream) {
    const float* X   = (const float*)d_in[0];
    const int*   A   = (const int*)  d_in[1];
    const float* W   = (const float*)d_in[2];
    const float* b   = (const float*)d_in[3];
    const float* att = (const float*)d_in[4];
    float* out = (float*)d_out;

    char* ws = (char*)d_ws;
    unsigned short* HbfT = (unsigned short*)ws;                    // 2 MB
    size_t off = (size_t)NH * FOUT * NN * 2;
    float* s_buf   = (float*)(ws + off);  off += (size_t)NH * NN * 4;
    float* d_buf   = (float*)(ws + off);  off += (size_t)NH * NN * 4;
    float* es_buf  = (float*)(ws + off);  off += (size_t)NH * NN * 4;
    float* es2_buf = (float*)(ws + off);  off += (size_t)NH * NN * 4;
    float* ed_buf  = (float*)(ws + off);  off += (size_t)NH * NN * 4;
    float* ed2_buf = (float*)(ws + off);  off += (size_t)NH * NN * 4;
    unsigned long long* Abits = (unsigned long long*)(ws + off);
    off += (size_t)NN * 64 * 8;                                         // 2 MB
    float* Hrow   = (float*)(ws + off);
    off += (size_t)NH * NN * FOUT * 4;                                  // 4 MB
    float* outH   = (float*)(ws + off);
    off += (size_t)NH * NN * FOUT * 4;                                  // 4 MB

    pack_bits<<<NN, 256, 0, stream>>>(A, Abits);
    gat_prep<<<dim3(128, 4), 256, 0, stream>>>(X, W, b, att, HbfT, Hrow,
                                               s_buf, d_buf,
                                               es_buf, es2_buf, ed_buf, ed2_buf);
    gat_main<<<512, 512, 0, stream>>>((const unsigned*)Abits, HbfT,
                                      s_buf, d_buf,
                                      es_buf, es2_buf, ed_buf, ed2_buf,
                                      Hrow, outH);
    gat_fin<<<256, 256, 0, stream>>>(outH, out);
}